// Round 1
// baseline (260.011 us; speedup 1.0000x reference)
//
#include <hip/hip_runtime.h>

// IndexNSW R5: coalesced row staging + speculative pick/prefetch.
// One WAVE per query (B=64 blocks x 64 threads), zero barriers (single-wave
// lockstep; DS ops are program-ordered within a wave).
//
// R5 changes vs R4 (104us/dispatch):
//  - row-per-instruction staging via global_load_lds: instr j loads the whole
//    1KB row of neighbor j (lane l fetches chunk l^(j&7); LDS dest linear,
//    source pre-swizzled) -> 8 contiguous 128B lines per instr instead of 64
//    scattered ones, 256 L1 transactions/step instead of 2048, and no 128-VGPR
//    r[32] staging array.
//  - distances read back from LDS with the inverse chunk swizzle (4-way bank
//    conflict, was 32-way unswizzled); per-lane accumulation order is
//    bit-identical to R4 (same chunk order, same fmaf chains, same shfl(32)).
//  - speculative early pick: before the merge, the reference pick is computed
//    directly on the union (old pool U fresh cands) via a 6-step u64
//    (flag,d,cidx) min-reduce; graph[uspec] is prefetched as a VECTOR load
//    (vmcnt domain) so the merge's lgkmcnt waits don't drain it. The
//    post-merge true pick verifies uspec; mismatch is only possible when all
//    32 merged slots are expanded (rare) -> fallback reload.
// Merge key = (f32 bits of d)<<6 | concat idx: d>=0 so u64 order ==
// (d, idx) lexicographic == lax.top_k stable order, incl. duplicate-id ties.

#define DIMS   256
#define RDEG   32
#define EFPOOL 32
#define KOUT   10
#define NWORDS 3125     // ceil(100000 / 32)
#define INF_D  1e30f

typedef unsigned long long u64;

__global__ __launch_bounds__(64, 1) void nsw_wave_kernel(
    const float* __restrict__ query,    // [B, 256]
    const float* __restrict__ storage,  // [N, 256]
    const int*   __restrict__ graph,    // [N, 32]
    const int*   __restrict__ initial,  // [B, 32]
    float*       __restrict__ out,      // [B*10 ids as float][B*10 dists]
    int B)
{
    __shared__ unsigned int visited[NWORDS];
    __shared__ unsigned int expanded[NWORDS];
    __shared__ float4 qsh[DIMS / 4];          // query row, 64 float4
    __shared__ float  rows[RDEG * DIMS];      // 32KB staged rows (chunk-swizzled)
    __shared__ u64    keys[64];               // merge keys
    __shared__ float  sc_d[EFPOOL];           // merge scatter scratch
    __shared__ int    sc_id[EFPOOL];

    const int l    = threadIdx.x;   // 0..63
    const int b    = blockIdx.x;
    const int nb   = l & 31;        // neighbor / pool slot owned (dup across halves)
    const int half = l >> 5;        // which 128-dim half this lane covers
    const int sw   = nb & 7;        // read-back chunk swizzle for my row

    for (int i = l; i < NWORDS; i += 64) { visited[i] = 0u; expanded[i] = 0u; }

    // stage query row to LDS (coalesced: lane l -> float4 l)
    qsh[l] = reinterpret_cast<const float4*>(query + (size_t)b * DIMS)[l];

    float pool_d  = INF_D;   // dummy pool; first merge sorts the real entries in
    int   pool_id = 0;
    int   u       = 0;       // node expanded this step (valid from s==1)
    int   nbid    = initial[b * EFPOOL + nb];   // per-lane id of slot nb

    for (int s = 0; s <= EFPOOL; ++s) {        // s==0: initial pool, then 32 steps
        const bool is_init = (s == 0);

        // mark current u expanded (sole writer; precedes this step's picks)
        if (!is_init && l == 0) expanded[u >> 5] |= 1u << (u & 31);

        // ---- coalesced row staging: instr j loads ALL of row gid[j] ----
        // lane l fetches global chunk l^(j&7); LDS dest is linear (lane*16B),
        // so LDS slot c holds chunk c^(j&7) -> reader applies same XOR.
        #pragma unroll
        for (int j = 0; j < RDEG; ++j) {
            int gidj = __shfl(nbid, j, 64);    // slot j's id (wave-uniform value)
            const float* src = storage + (size_t)gidj * DIMS + ((l ^ (j & 7)) << 2);
            __builtin_amdgcn_global_load_lds(
                (const __attribute__((address_space(1))) void*)src,
                (__attribute__((address_space(3))) void*)&rows[j * DIMS], 16, 0, 0);
        }

        // visited bookkeeping (LDS; overlaps the staging loads).
        // read-all precedes OR: program order => duplicates in this set all
        // see the pre-update state, same as the reference.
        unsigned vw = visited[nbid >> 5];
        bool fresh = is_init ? true : !((vw >> (nbid & 31)) & 1u);
        if ((l < 32) && fresh) atomicOr(&visited[nbid >> 5], 1u << (nbid & 31));

        // ---- wait all rows landed in LDS, then distances (R4-identical) ----
        asm volatile("s_waitcnt vmcnt(0)" ::: "memory");
        float a0 = 0.f, a1 = 0.f, a2 = 0.f, a3 = 0.f;
        {
            const float4* rp = reinterpret_cast<const float4*>(rows) + nb * 64 + half * 32;
            const float4* qp = qsh + half * 32;
            #pragma unroll
            for (int j = 0; j < 32; ++j) {
                float4 r = rp[j ^ sw];         // inverse chunk swizzle
                float4 q = qp[j];
                float d0 = r.x - q.x; a0 = fmaf(d0, d0, a0);
                float d1 = r.y - q.y; a1 = fmaf(d1, d1, a1);
                float d2 = r.z - q.z; a2 = fmaf(d2, d2, a2);
                float d3 = r.w - q.w; a3 = fmaf(d3, d3, a3);
            }
        }
        float part = (a0 + a1) + (a2 + a3);
        float d  = part + __shfl_xor(part, 32, 64);   // halves have same row
        float nd = fresh ? d : INF_D;

        // ---- early pick: reference pick computed on the union, pre-merge ----
        // key = (flagged, d, concat idx); flagged = expanded (pool) / !fresh
        // (cands). Equals the post-merge pick unless all 32 merged slots are
        // expanded (then the verified fallback below corrects it).
        bool eflag = half ? (!fresh)
                          : (((expanded[pool_id >> 5] >> (pool_id & 31)) & 1u) != 0u);
        float ed_e = half ? nd : pool_d;
        u64 ek = ((u64)(eflag ? 1u : 0u) << 62)
               | ((u64)__float_as_uint(ed_e) << 6) | (unsigned)l;
        #pragma unroll
        for (int m = 1; m < 64; m <<= 1) {
            u64 o = __shfl_xor(ek, m, 64);
            ek = (o < ek) ? o : ek;
        }
        int cidx  = (int)(ek & 63);
        int myid  = half ? nbid : pool_id;
        int uspec = __shfl(myid, cidx, 64);

        // prefetch graph row of the speculative pick as a VECTOR load: it sits
        // in the vmcnt domain, so the merge's lgkmcnt waits don't drain it.
        int nnbid = graph[(size_t)uspec * RDEG + nb];

        // ---- merge (unchanged from R4): 64 concat elems -> sorted top-32 ----
        {
            float ed  = half ? nd   : pool_d;
            int   eid = half ? nbid : pool_id;
            u64 key = ((u64)__float_as_uint(ed) << 6) | (unsigned)l;
            keys[l] = key;
            int rank = 0;
            #pragma unroll
            for (int j = 0; j < 64; ++j)            // same addr all lanes: broadcast
                rank += (keys[j] < key) ? 1 : 0;
            if (rank < EFPOOL) { sc_d[rank] = ed; sc_id[rank] = eid; }  // ranks unique
            pool_d  = sc_d[nb];                     // in-order DS: no barrier
            pool_id = sc_id[nb];
        }

        // ---- true pick + speculation verify ----
        {
            bool unexp = !((expanded[pool_id >> 5] >> (pool_id & 31)) & 1u);
            u64 bm = __ballot(unexp && (l < 32));
            int slot = (bm == 0ull) ? 0 : (__ffsll(bm) - 1);
            int utrue = sc_id[slot];                // uniform slot: broadcast read
            int ut = __builtin_amdgcn_readfirstlane(utrue);
            int us = __builtin_amdgcn_readfirstlane(uspec);
            if (ut != us) {                         // rare: redo graph fetch
                nnbid = graph[(size_t)ut * RDEG + nb];
            }
            u = utrue;
        }
        nbid = nnbid;
    }

    // ---- output: pool sorted ascending; ids as float (exact < 2^24), then dists ----
    if (l < KOUT) {
        out[b * KOUT + l]            = (float)pool_id;
        out[B * KOUT + b * KOUT + l] = pool_d;
    }
}

extern "C" void kernel_launch(void* const* d_in, const int* in_sizes, int n_in,
                              void* d_out, int out_size, void* d_ws, size_t ws_size,
                              hipStream_t stream) {
    const float* query   = (const float*)d_in[0];
    const float* storage = (const float*)d_in[1];
    const int*   graph   = (const int*)d_in[2];
    const int*   initial = (const int*)d_in[3];
    float* out = (float*)d_out;

    const int B = in_sizes[0] / DIMS;   // 64

    nsw_wave_kernel<<<B, 64, 0, stream>>>(query, storage, graph, initial, out, B);
}

// Round 2
// 243.094 us; speedup vs baseline: 1.0696x; 1.0696x over previous
//
#include <hip/hip_runtime.h>

// IndexNSW R6: R4 staging (lane-per-row VGPR loads) + fresh-masked loads +
// speculative graph prefetch. One WAVE per query (B=64 blocks x 64 threads),
// zero barriers (single-wave lockstep; DS ops are program-ordered).
//
// R6 changes vs R5 (131us) / R4 (104us):
//  - REVERT R5's global_load_lds staging (lost ~2000cy/step to 32 serial
//    shfl->M0->issue chains + hard vmcnt(0) + LDS readback). Back to R4's
//    lane-per-row float4 loads into VGPRs.
//  - fresh-MASKED loads: storage phase is MSHR/line-parallelism bound
//    (~256 lines demanded, ~64-70 in flight per CU => ~4 serialized HBM
//    rounds). Visited rows' distances are INF-masked anyway, so skip their
//    loads entirely: the ~120cy LDS visited read up front cuts line demand
//    by the revisit fraction.
//  - speculative pick (validated in R5) with a CHEAPER 32-bit key:
//    (flag<<31)|((dbits>>13)<<6)|lane. Truncating d can mispredict near-ties;
//    the readfirstlane verify + graph reload fallback makes any mispredict
//    a perf blip, never a correctness issue. Graph row of uspec is issued
//    before the merge so its ~900cy hides under the ~700cy merge.
//  - last iteration skips spec/graph-prefetch (was dead work).
// Merge key = (f32 bits of d)<<6 | concat idx: d>=0 so u64 order ==
// (d, idx) lexicographic == lax.top_k stable order, incl. duplicate-id ties.

#define DIMS   256
#define RDEG   32
#define EFPOOL 32
#define KOUT   10
#define NWORDS 3125     // ceil(100000 / 32)
#define INF_D  1e30f

typedef unsigned long long u64;

__global__ __launch_bounds__(64, 1) void nsw_wave_kernel(
    const float* __restrict__ query,    // [B, 256]
    const float* __restrict__ storage,  // [N, 256]
    const int*   __restrict__ graph,    // [N, 32]
    const int*   __restrict__ initial,  // [B, 32]
    float*       __restrict__ out,      // [B*10 ids as float][B*10 dists]
    int B)
{
    __shared__ unsigned int visited[NWORDS];
    __shared__ unsigned int expanded[NWORDS];
    __shared__ float4 qsh[DIMS / 4];            // query row, 64 float4
    __shared__ u64    keys[64];                 // merge keys
    __shared__ float  sc_d[EFPOOL];             // merge scatter scratch
    __shared__ int    sc_id[EFPOOL];

    const int l    = threadIdx.x;   // 0..63
    const int b    = blockIdx.x;
    const int nb   = l & 31;        // neighbor / pool slot owned (dup across halves)
    const int half = l >> 5;        // which 128-dim half this lane covers

    for (int i = l; i < NWORDS; i += 64) { visited[i] = 0u; expanded[i] = 0u; }

    // stage query row to LDS (coalesced: lane l -> float4 l)
    qsh[l] = reinterpret_cast<const float4*>(query + (size_t)b * DIMS)[l];

    float pool_d  = INF_D;   // dummy pool; first merge sorts the real entries in
    int   pool_id = 0;
    int   u       = 0;       // node expanded this step (valid from s==1)
    int   nbid    = initial[b * EFPOOL + nb];   // per-lane id of slot nb

    for (int s = 0; s <= EFPOOL; ++s) {        // s==0: initial pool, then 32 steps
        const bool is_init = (s == 0);

        // mark current u expanded (sole writer; precedes this step's picks)
        if (!is_init && l == 0) expanded[u >> 5] |= 1u << (u & 31);

        // visited bookkeeping. read-all precedes OR (program order) =>
        // duplicates in this step's set all see pre-update state, as in ref.
        unsigned vw = visited[nbid >> 5];
        bool fresh = is_init ? true : !((vw >> (nbid & 31)) & 1u);
        if ((l < 32) && fresh) atomicOr(&visited[nbid >> 5], 1u << (nbid & 31));

        // ---- fresh-masked lane-per-row staging + distance (R4-identical
        // numerics for fresh rows; non-fresh rows are INF-masked, rows unused)
        float part = 0.f;
        if (fresh) {
            const float4* sp = reinterpret_cast<const float4*>(
                storage + (size_t)nbid * DIMS) + half * 32;
            float4 r[32];
            #pragma unroll
            for (int j = 0; j < 32; ++j) r[j] = sp[j];   // loads in flight
            float a0 = 0.f, a1 = 0.f, a2 = 0.f, a3 = 0.f;
            #pragma unroll
            for (int j = 0; j < 32; ++j) {
                float4 q = qsh[half * 32 + j];
                float d0 = r[j].x - q.x; a0 = fmaf(d0, d0, a0);
                float d1 = r[j].y - q.y; a1 = fmaf(d1, d1, a1);
                float d2 = r[j].z - q.z; a2 = fmaf(d2, d2, a2);
                float d3 = r[j].w - q.w; a3 = fmaf(d3, d3, a3);
            }
            part = (a0 + a1) + (a2 + a3);
        }
        // pair lanes l, l^32 share nb => same nbid => same fresh: shfl pair
        // is either fully active (valid exchange) or fully inactive (unused).
        float d  = part + __shfl_xor(part, 32, 64);
        float nd = fresh ? d : INF_D;

        int nnbid = nbid;                      // next step's neighbor ids
        int uspec = -1;
        if (s < EFPOOL) {
            // ---- early pick: reference pick computed on the union, pre-merge.
            // 32-bit key: (flagged<<31)|((dbits>>13)<<6)|lane. d>=0 => dbits
            // <2^31 => (dbits>>13)<<6 fits bits 6..30; flag dominates. Mantissa
            // truncation can mispredict near-ties -> caught by verify below.
            bool eflag = half ? (!fresh)
                              : (((expanded[pool_id >> 5] >> (pool_id & 31)) & 1u) != 0u);
            float ed_e = half ? nd : pool_d;
            unsigned ek = ((eflag ? 1u : 0u) << 31)
                        | ((__float_as_uint(ed_e) >> 13) << 6) | (unsigned)l;
            #pragma unroll
            for (int m = 1; m < 64; m <<= 1) {
                unsigned o = __shfl_xor((int)ek, m, 64);
                ek = (o < ek) ? o : ek;
            }
            int cidx  = (int)(ek & 63);
            int myid  = half ? nbid : pool_id;
            uspec = __shfl(myid, cidx, 64);
            // prefetch graph row of the speculative pick (vmcnt domain; the
            // merge's lgkmcnt waits don't drain it) -> ~900cy hidden by merge
            nnbid = graph[(size_t)uspec * RDEG + nb];
        }

        // ---- merge: 64 concat elems -> sorted top-32 (== lax.top_k) ----
        {
            float ed  = half ? nd   : pool_d;
            int   eid = half ? nbid : pool_id;
            u64 key = ((u64)__float_as_uint(ed) << 6) | (unsigned)l;
            keys[l] = key;
            int rank = 0;
            #pragma unroll
            for (int j = 0; j < 64; ++j)            // same addr all lanes: broadcast
                rank += (keys[j] < key) ? 1 : 0;
            if (rank < EFPOOL) { sc_d[rank] = ed; sc_id[rank] = eid; }  // ranks unique
            pool_d  = sc_d[nb];                     // in-order DS: no barrier
            pool_id = sc_id[nb];
        }

        // ---- true pick + speculation verify ----
        if (s < EFPOOL) {
            bool unexp = !((expanded[pool_id >> 5] >> (pool_id & 31)) & 1u);
            u64 bm = __ballot(unexp && (l < 32));
            int slot = (bm == 0ull) ? 0 : (__ffsll(bm) - 1);
            int utrue = sc_id[slot];                // uniform slot: broadcast read
            int ut = __builtin_amdgcn_readfirstlane(utrue);
            int us = __builtin_amdgcn_readfirstlane(uspec);
            if (ut != us) {                         // mispredict: redo graph fetch
                nnbid = graph[(size_t)ut * RDEG + nb];
            }
            u = utrue;
        }
        nbid = nnbid;
    }

    // ---- output: pool sorted ascending; ids as float (exact < 2^24), then dists ----
    if (l < KOUT) {
        out[b * KOUT + l]            = (float)pool_id;
        out[B * KOUT + b * KOUT + l] = pool_d;
    }
}

extern "C" void kernel_launch(void* const* d_in, const int* in_sizes, int n_in,
                              void* d_out, int out_size, void* d_ws, size_t ws_size,
                              hipStream_t stream) {
    const float* query   = (const float*)d_in[0];
    const float* storage = (const float*)d_in[1];
    const int*   graph   = (const int*)d_in[2];
    const int*   initial = (const int*)d_in[3];
    float* out = (float*)d_out;

    const int B = in_sizes[0] / DIMS;   // 64

    nsw_wave_kernel<<<B, 64, 0, stream>>>(query, storage, graph, initial, out, B);
}

// Round 3
// 241.980 us; speedup vs baseline: 1.0745x; 1.0046x over previous
//
#include <hip/hip_runtime.h>

// IndexNSW R7: R4 structure + cheap coalesced row staging (discriminating
// experiment: TA-transaction-bound vs line-fill-bound storage phase).
// One WAVE per query (B=64 blocks x 64 threads), zero barriers.
//
// R7 changes vs R6 (112us) / R4 (104us):
//  - DROP fresh-masking (graph is uniform-random -> ~1% revisits; the gate
//    only added a serial visited-read before load issue) and DROP the
//    speculative pick (its ~400cy/step overhead ~= the ~500cy graph-hide).
//    Everything except staging is byte-identical to R4.
//  - Staging: instruction j loads slot-j's ENTIRE 1KB row coalesced via
//    global_load_lds (8 cache lines/instr instead of 64 scattered 16B
//    transactions). Row id broadcast via v_readlane (not shfl), address math
//    scalar (row base in SGPRs) + one v_xor for the lane chunk -> ~6 instr
//    per row vs R5's ~12 (R5's loss was this overhead, not the DMA).
//  - Source XOR-swizzle (m173 pattern): lane l fetches chunk l^j; LDS dest
//    linear => LDS slot c of row j holds chunk c^j. Read-back of chunk k of
//    row nb = slot k^nb => per-instruction banks spread over all 8 4-bank
//    groups (8 lanes x 16B each) = conflict-free at the b128 minimum.
//  - Distance fmaf chain reads LDS in R4's exact order: bit-identical d,
//    bit-identical trajectory, bit-identical output.
// Merge key = (f32 bits of d)<<6 | concat idx: d>=0 so u64 order ==
// (d, idx) lexicographic == lax.top_k stable order, incl. duplicate-id ties.

#define DIMS   256
#define RDEG   32
#define EFPOOL 32
#define KOUT   10
#define NWORDS 3125     // ceil(100000 / 32)
#define INF_D  1e30f

typedef unsigned long long u64;

__global__ __launch_bounds__(64, 1) void nsw_wave_kernel(
    const float* __restrict__ query,    // [B, 256]
    const float* __restrict__ storage,  // [N, 256]
    const int*   __restrict__ graph,    // [N, 32]
    const int*   __restrict__ initial,  // [B, 32]
    float*       __restrict__ out,      // [B*10 ids as float][B*10 dists]
    int B)
{
    __shared__ unsigned int visited[NWORDS];
    __shared__ unsigned int expanded[NWORDS];
    __shared__ float4 qsh[DIMS / 4];            // query row, 64 float4
    __shared__ float4 rows[RDEG * (DIMS / 4)];  // 32 rows x 64 chunks = 32KB
    __shared__ u64    keys[64];                 // merge keys
    __shared__ float  sc_d[EFPOOL];             // merge scatter scratch
    __shared__ int    sc_id[EFPOOL];

    const int l    = threadIdx.x;   // 0..63
    const int b    = blockIdx.x;
    const int nb   = l & 31;        // neighbor / pool slot owned (dup across halves)
    const int half = l >> 5;        // which 128-dim half this lane covers

    for (int i = l; i < NWORDS; i += 64) { visited[i] = 0u; expanded[i] = 0u; }

    // stage query row to LDS (coalesced: lane l -> float4 l)
    qsh[l] = reinterpret_cast<const float4*>(query + (size_t)b * DIMS)[l];

    float pool_d  = INF_D;   // dummy pool; first merge sorts the real entries in
    int   pool_id = 0;
    int   u       = 0;       // node expanded this step (valid from s==1)
    int   nbid    = initial[b * EFPOOL + nb];   // per-lane id of slot nb

    const int vboff = l << 4;       // lane byte offset within a 1KB row

    for (int s = 0; s <= EFPOOL; ++s) {        // s==0: initial pool, then 32 steps
        const bool is_init = (s == 0);

        // mark previous u expanded (sole writer; precedes this step's pick)
        if (!is_init && l == 0) expanded[u >> 5] |= 1u << (u & 31);

        // ---- coalesced staging: instr j loads ALL of slot-j's row ----
        // lane l fetches byte (l^j)*16 of the row; LDS dest linear, so LDS
        // slot c holds chunk c^j (source-swizzle, global_load_lds-compatible).
        #pragma unroll
        for (int j = 0; j < RDEG; ++j) {
            int gid = __builtin_amdgcn_readlane(nbid, j);   // uniform row id
            const char* src = (const char*)(storage + (size_t)gid * DIMS)
                            + (vboff ^ (j << 4));
            __builtin_amdgcn_global_load_lds(
                (const __attribute__((address_space(1))) void*)src,
                (__attribute__((address_space(3))) void*)&rows[j * (DIMS / 4)],
                16, 0, 0);
        }

        // visited bookkeeping (overlaps the staging fills).
        // read-all precedes OR (program order) => duplicates in this step's
        // set all see pre-update state, same as the reference.
        unsigned vw = visited[nbid >> 5];
        bool fresh = is_init ? true : !((vw >> (nbid & 31)) & 1u);
        if ((l < 32) && fresh) atomicOr(&visited[nbid >> 5], 1u << (nbid & 31));

        // ---- wait rows landed, then distance: R4's EXACT fmaf chain ----
        asm volatile("s_waitcnt vmcnt(0)" ::: "memory");
        float a0 = 0.f, a1 = 0.f, a2 = 0.f, a3 = 0.f;
        {
            const float4* rp = rows + nb * (DIMS / 4);
            const float4* qp = qsh + half * 32;
            #pragma unroll
            for (int j = 0; j < 32; ++j) {
                float4 r = rp[(half * 32 + j) ^ nb];   // inverse source swizzle
                float4 q = qp[j];
                float d0 = r.x - q.x; a0 = fmaf(d0, d0, a0);
                float d1 = r.y - q.y; a1 = fmaf(d1, d1, a1);
                float d2 = r.z - q.z; a2 = fmaf(d2, d2, a2);
                float d3 = r.w - q.w; a3 = fmaf(d3, d3, a3);
            }
        }
        float part = (a0 + a1) + (a2 + a3);
        float d  = part + __shfl_xor(part, 32, 64);   // halves share a row
        float nd = fresh ? d : INF_D;

        // ---- merge: 64 concat elems -> sorted top-32 (== lax.top_k) ----
        {
            float ed  = half ? nd   : pool_d;
            int   eid = half ? nbid : pool_id;
            u64 key = ((u64)__float_as_uint(ed) << 6) | (unsigned)l;
            keys[l] = key;
            int rank = 0;
            #pragma unroll
            for (int j = 0; j < 64; ++j)            // same addr all lanes: broadcast
                rank += (keys[j] < key) ? 1 : 0;
            if (rank < EFPOOL) { sc_d[rank] = ed; sc_id[rank] = eid; }  // ranks unique
            pool_d  = sc_d[nb];                     // in-order DS: no barrier
            pool_id = sc_id[nb];
        }

        // ---- pick next u = first unexpanded slot; fetch its graph row ----
        if (s < EFPOOL) {
            bool unexp = !((expanded[pool_id >> 5] >> (pool_id & 31)) & 1u);
            u64 bm = __ballot(unexp && (l < 32));
            int slot = (bm == 0ull) ? 0 : (__ffsll(bm) - 1);
            u = sc_id[slot];                        // uniform slot: broadcast read
            nbid = graph[(size_t)u * RDEG + nb];    // 128B row, 1-2 lines
        }
    }

    // ---- output: pool sorted ascending; ids as float (exact < 2^24), then dists ----
    if (l < KOUT) {
        out[b * KOUT + l]            = (float)pool_id;
        out[B * KOUT + b * KOUT + l] = pool_d;
    }
}

extern "C" void kernel_launch(void* const* d_in, const int* in_sizes, int n_in,
                              void* d_out, int out_size, void* d_ws, size_t ws_size,
                              hipStream_t stream) {
    const float* query   = (const float*)d_in[0];
    const float* storage = (const float*)d_in[1];
    const int*   graph   = (const int*)d_in[2];
    const int*   initial = (const int*)d_in[3];
    float* out = (float*)d_out;

    const int B = in_sizes[0] / DIMS;   // 64

    nsw_wave_kernel<<<B, 64, 0, stream>>>(query, storage, graph, initial, out, B);
}